// Round 1
// 1687.337 us; speedup vs baseline: 1.1088x; 1.1088x over previous
//
#include <hip/hip_runtime.h>

#define B_ROWS 256
#define D_DIM 1024
#define C_TOT 100000
#define C_PAD 100096          // 782*128, padded column count
#define N_CTILES 782
#define K_UNITS2 1564         // C_PAD/64 (BK=64 units)
#define SPLITK 32
#define KC_ITERS 49           // ceil(1564/32)
#define STEPS 5

typedef _Float16 half8 __attribute__((ext_vector_type(8)));
typedef _Float16 half4v __attribute__((ext_vector_type(4)));
typedef float floatx4 __attribute__((ext_vector_type(4)));

// ---------------- async global->LDS (width 16) ----------------
__device__ __forceinline__ void gld16(const void* g, void* l) {
    __builtin_amdgcn_global_load_lds(
        (const __attribute__((address_space(1))) unsigned int*)g,
        (__attribute__((address_space(3))) unsigned int*)l,
        16, 0, 0);
}

// Stage a 16 KB tile (128 rows x 128 bytes = BK=64 fp16) from global
// (row stride strideB bytes) into contiguous LDS. 256 threads, 4 x 16B
// chunks per thread. LDS dest is wave-uniform base + lane*16 (HW), so
// chunk id (t + 256*h) lands at LDS byte id*16. The global SOURCE column
// is pre-swizzled (col ^= row&7) so that the matching swizzled ds_read
// is bank-spread (rule 21: swizzle both sides or neither).
__device__ __forceinline__ void stage_tile64(const char* gbase, size_t strideB,
                                             char* lds, int t) {
    const int w = t >> 6;
#pragma unroll
    for (int h = 0; h < 4; ++h) {
        const int id = t + 256 * h;
        const int row = id >> 3;
        const int col = (id & 7) ^ (row & 7);  // pre-swizzled source chunk
        gld16(gbase + (size_t)row * strideB + (col << 4),
              lds + h * 4096 + (w << 10));
    }
}

// Swizzled fragment read: LDS[r][x] holds global[r][x ^ (r&7)] (16B units),
// so global half-col kh is read at half index kh ^ ((r&7)<<3).
__device__ __forceinline__ half8 ldfrag(const _Float16* base, int r, int kh) {
    return *(const half8*)&base[r * 64 + (kh ^ ((r & 7) << 3))];
}

__device__ __forceinline__ float sum8(half8 v) {
    return (float)v[0] + (float)v[1] + (float)v[2] + (float)v[3] +
           (float)v[4] + (float)v[5] + (float)v[6] + (float)v[7];
}

// ---------------- prep: memory norms + fp16 cast ----------------
__global__ __launch_bounds__(64) void prep_mem_kernel(
    const float* __restrict__ mem, _Float16* __restrict__ memH,
    float* __restrict__ s_c) {
    const int c = blockIdx.x;
    const int lane = threadIdx.x;
    half8* dst = (half8*)(memH + (size_t)c * D_DIM);
    if (c >= C_TOT) {
        half8 z = {};
        dst[lane] = z;
        dst[lane + 64] = z;
        if (lane == 0) s_c[c] = 0.f;
        return;
    }
    const float4* src = (const float4*)(mem + (size_t)c * D_DIM);
    float ss = 0.f;
#pragma unroll
    for (int h = 0; h < 2; ++h) {
        const int i = lane + 64 * h;
        float4 a = src[2 * i], b = src[2 * i + 1];
        ss += a.x * a.x + a.y * a.y + a.z * a.z + a.w * a.w;
        ss += b.x * b.x + b.y * b.y + b.z * b.z + b.w * b.w;
        half8 hv = {(_Float16)a.x, (_Float16)a.y, (_Float16)a.z, (_Float16)a.w,
                    (_Float16)b.x, (_Float16)b.y, (_Float16)b.z, (_Float16)b.w};
        dst[i] = hv;
    }
    for (int off = 32; off; off >>= 1) ss += __shfl_xor(ss, off, 64);
    if (lane == 0) s_c[c] = 1.f / fmaxf(sqrtf(ss), 1e-8f);
}

// ---------------- prep: transpose memH [C_PAD][D] -> memT [D][C_PAD] -------
__global__ __launch_bounds__(256) void transpose_kernel(
    const _Float16* __restrict__ src, _Float16* __restrict__ dst) {
    __shared__ _Float16 tile[64][72];
    const int c0 = blockIdx.x * 64;
    const int d0 = blockIdx.y * 64;
    const int t = threadIdx.x;
    const int r = t >> 2, cg = t & 3;
    const half8* s8 = (const half8*)(src + (size_t)(c0 + r) * D_DIM + d0 + cg * 16);
    half8 v0 = s8[0], v1 = s8[1];
    *(half8*)&tile[r][cg * 16] = v0;
    *(half8*)&tile[r][cg * 16 + 8] = v1;
    __syncthreads();
    alignas(16) _Float16 o[16];
#pragma unroll
    for (int i = 0; i < 16; ++i) o[i] = tile[cg * 16 + i][r];
    half8* d8 = (half8*)(dst + (size_t)(d0 + r) * C_PAD + c0 + cg * 16);
    d8[0] = *(half8*)&o[0];
    d8[1] = *(half8*)&o[8];
}

// ---------------- step-0 prep: current norms + fp16 cast + zero num/den ---
__global__ __launch_bounds__(64) void prep_cur_kernel(
    const float* __restrict__ cur, _Float16* __restrict__ cuH,
    float* __restrict__ num, float* __restrict__ den) {
    const int b = blockIdx.x;
    const int lane = threadIdx.x;
    const float4* src = (const float4*)(cur + (size_t)b * D_DIM);
    float4 v[4];
    float ss = 0.f;
#pragma unroll
    for (int i = 0; i < 4; ++i) {
        v[i] = src[i * 64 + lane];
        ss += v[i].x * v[i].x + v[i].y * v[i].y + v[i].z * v[i].z + v[i].w * v[i].w;
    }
    for (int off = 32; off; off >>= 1) ss += __shfl_xor(ss, off, 64);
    const float r = 1.f / fmaxf(sqrtf(ss), 1e-8f);
    half4v* dst = (half4v*)(cuH + (size_t)b * D_DIM);
#pragma unroll
    for (int i = 0; i < 4; ++i) {
        half4v h = {(_Float16)(v[i].x * r), (_Float16)(v[i].y * r),
                    (_Float16)(v[i].z * r), (_Float16)(v[i].w * r)};
        dst[i * 64 + lane] = h;
    }
    float4 z = {0.f, 0.f, 0.f, 0.f};
    float4* nz = (float4*)(num + (size_t)b * D_DIM);
#pragma unroll
    for (int i = 0; i < 4; ++i) nz[i * 64 + lane] = z;
    if (lane == 0) den[b] = 0.f;
}

// ---------------- GEMM1: P = exp((cuH . memH^T) * s_c), fp16 out ----------
// grid (2, 782), 256 threads, 128x128 tile, BK=64, mfma 16x16x32 f16.
// Bijective XCD swizzle co-locates m-tile pairs (sharing the memH panel)
// on one XCD so the B-panel is fetched once per XCD-L2, not twice.
__global__ __launch_bounds__(256) void gemm1_kernel(
    const _Float16* __restrict__ cuH, const _Float16* __restrict__ memH,
    const float* __restrict__ s_c, _Float16* __restrict__ P) {
    __shared__ _Float16 At[128 * 64];
    __shared__ _Float16 Bt[128 * 64];
    const int t = threadIdx.x;
    const int lane = t & 63, w = t >> 6;
    const int lm = lane & 15, q = lane >> 4;
    const int wm = (w >> 1) << 6, wn = (w & 1) << 6;
    // nwg = 1564 = 8*195+4 -> chunks: xcd<4 get 196, xcd>=4 get 195 (m204)
    const int orig = blockIdx.x + (blockIdx.y << 1);
    const int xcd = orig & 7, lid = orig >> 3;
    const int wg = (xcd < 4 ? xcd * 196 : 784 + (xcd - 4) * 195) + lid;
    const int tm0 = (wg & 1) << 7;
    const int tn0 = (wg >> 1) << 7;
    const char* gA = (const char*)cuH + (size_t)tm0 * 2048;
    const char* gB = (const char*)memH + (size_t)tn0 * 2048;
    floatx4 acc[4][4];
#pragma unroll
    for (int i = 0; i < 4; ++i)
#pragma unroll
        for (int j = 0; j < 4; ++j) acc[i][j] = (floatx4){0.f, 0.f, 0.f, 0.f};

    for (int kt = 0; kt < 16; ++kt) {
        __syncthreads();
        stage_tile64(gA + kt * 128, 2048, (char*)At, t);
        stage_tile64(gB + kt * 128, 2048, (char*)Bt, t);
        __syncthreads();
#pragma unroll
        for (int ks = 0; ks < 2; ++ks) {
            half8 af[4], bf[4];
#pragma unroll
            for (int i = 0; i < 4; ++i)
                af[i] = ldfrag(At, wm + i * 16 + lm, ks * 32 + q * 8);
#pragma unroll
            for (int j = 0; j < 4; ++j)
                bf[j] = ldfrag(Bt, wn + j * 16 + lm, ks * 32 + q * 8);
#pragma unroll
            for (int i = 0; i < 4; ++i)
#pragma unroll
                for (int j = 0; j < 4; ++j)
                    acc[i][j] = __builtin_amdgcn_mfma_f32_16x16x32_f16(
                        af[i], bf[j], acc[i][j], 0, 0, 0);
        }
    }
    // epilogue: C/D layout col=lane&15, row=(lane>>4)*4+reg (verified m89/m91)
#pragma unroll
    for (int i = 0; i < 4; ++i) {
        const int m0 = tm0 + wm + i * 16 + q * 4;
#pragma unroll
        for (int j = 0; j < 4; ++j) {
            const int c = tn0 + wn + j * 16 + lm;
            const float sc = s_c[c];
            const bool valid = (c < C_TOT);
#pragma unroll
            for (int r = 0; r < 4; ++r) {
                float vv = valid ? __expf(acc[i][j][r] * sc) : 0.f;
                P[(size_t)(m0 + r) * C_PAD + c] = (_Float16)vv;
            }
        }
    }
}

// ---------------- GEMM2: num += P . mem (split-K) + den row-sums ----------
// grid (16 tiles, SPLITK), A = P [256][C_PAD], B^T = memT [1024][C_PAD].
// n-tile-0 blocks also accumulate den[b] = sum_c P[b][c] from the staged
// A fragments (each A element loaded by exactly the wn==0 waves once).
__global__ __launch_bounds__(256) void gemm2_kernel(
    const _Float16* __restrict__ P, const _Float16* __restrict__ memT,
    float* __restrict__ num, float* __restrict__ den) {
    __shared__ _Float16 At[128 * 64];
    __shared__ _Float16 Bt[128 * 64];
    const int t = threadIdx.x;
    const int lane = t & 63, w = t >> 6;
    const int lm = lane & 15, q = lane >> 4;
    const int wm = (w >> 1) << 6, wn = (w & 1) << 6;
    const int tm0 = (blockIdx.x >> 3) << 7;
    const int tn0 = (blockIdx.x & 7) << 7;
    const int kt0 = blockIdx.y * KC_ITERS;
    const int ktEnd = min(kt0 + KC_ITERS, K_UNITS2);
    const size_t strideB = (size_t)C_PAD * 2;
    const char* gA = (const char*)P + (size_t)tm0 * strideB;
    const char* gB = (const char*)memT + (size_t)tn0 * strideB;
    const bool do_den = ((blockIdx.x & 7) == 0) && (wn == 0);
    float rs[4] = {0.f, 0.f, 0.f, 0.f};
    floatx4 acc[4][4];
#pragma unroll
    for (int i = 0; i < 4; ++i)
#pragma unroll
        for (int j = 0; j < 4; ++j) acc[i][j] = (floatx4){0.f, 0.f, 0.f, 0.f};

    for (int kt = kt0; kt < ktEnd; ++kt) {
        __syncthreads();
        stage_tile64(gA + (size_t)kt * 128, strideB, (char*)At, t);
        stage_tile64(gB + (size_t)kt * 128, strideB, (char*)Bt, t);
        __syncthreads();
#pragma unroll
        for (int ks = 0; ks < 2; ++ks) {
            half8 af[4], bf[4];
#pragma unroll
            for (int i = 0; i < 4; ++i)
                af[i] = ldfrag(At, wm + i * 16 + lm, ks * 32 + q * 8);
#pragma unroll
            for (int j = 0; j < 4; ++j)
                bf[j] = ldfrag(Bt, wn + j * 16 + lm, ks * 32 + q * 8);
#pragma unroll
            for (int i = 0; i < 4; ++i)
#pragma unroll
                for (int j = 0; j < 4; ++j)
                    acc[i][j] = __builtin_amdgcn_mfma_f32_16x16x32_f16(
                        af[i], bf[j], acc[i][j], 0, 0, 0);
            if (do_den) {
#pragma unroll
                for (int i = 0; i < 4; ++i) rs[i] += sum8(af[i]);
            }
        }
    }
#pragma unroll
    for (int i = 0; i < 4; ++i) {
        const int m0 = tm0 + wm + i * 16 + q * 4;
#pragma unroll
        for (int j = 0; j < 4; ++j) {
            const int n = tn0 + wn + j * 16 + lm;
#pragma unroll
            for (int r = 0; r < 4; ++r)
                atomicAdd(&num[(size_t)(m0 + r) * D_DIM + n], acc[i][j][r]);
        }
    }
    if (do_den) {
#pragma unroll
        for (int i = 0; i < 4; ++i) {
            float v = rs[i];
            v += __shfl_xor(v, 16, 64);
            v += __shfl_xor(v, 32, 64);
            if (q == 0) atomicAdd(&den[tm0 + wm + i * 16 + lm], v);
        }
    }
}

// ---- update (fused): cur = 0.8*num/den + 0.2*cur; emit cuH; zero num/den --
__global__ __launch_bounds__(256) void update_kernel(
    float* __restrict__ num, float* __restrict__ den,
    const float* __restrict__ cin, float* __restrict__ cout,
    _Float16* __restrict__ cuH) {
    const int b = blockIdx.x;
    const int t = threadIdx.x;
    const float inv = 0.8f / den[b];
    float4* n4 = (float4*)(num + (size_t)b * D_DIM);
    const float4* c4 = (const float4*)(cin + (size_t)b * D_DIM);
    float4* o4 = (float4*)(cout + (size_t)b * D_DIM);
    float4 n = n4[t], c = c4[t];
    float4 o = {n.x * inv + 0.2f * c.x, n.y * inv + 0.2f * c.y,
                n.z * inv + 0.2f * c.z, n.w * inv + 0.2f * c.w};
    o4[t] = o;
    // row norm of the new current (for the next step's cosine sim)
    float ss = o.x * o.x + o.y * o.y + o.z * o.z + o.w * o.w;
    for (int off = 32; off; off >>= 1) ss += __shfl_xor(ss, off, 64);
    __shared__ float ws[4];
    if ((t & 63) == 0) ws[t >> 6] = ss;
    __syncthreads();
    ss = ws[0] + ws[1] + ws[2] + ws[3];
    const float r = 1.f / fmaxf(sqrtf(ss), 1e-8f);
    half4v h = {(_Float16)(o.x * r), (_Float16)(o.y * r),
                (_Float16)(o.z * r), (_Float16)(o.w * r)};
    ((half4v*)(cuH + (size_t)b * D_DIM))[t] = h;
    float4 z = {0.f, 0.f, 0.f, 0.f};
    n4[t] = z;  // zero num for next step (after read above)
    if (t == 0) den[b] = 0.f;
}

extern "C" void kernel_launch(void* const* d_in, const int* in_sizes, int n_in,
                              void* d_out, int out_size, void* d_ws, size_t ws_size,
                              hipStream_t stream) {
    const float* query = (const float*)d_in[0];  // [256][1024] f32
    const float* mem = (const float*)d_in[1];    // [100000][1024] f32
    float* out = (float*)d_out;                  // [256][1024] f32
    char* ws = (char*)d_ws;

    size_t off = 0;
    _Float16* memH = (_Float16*)(ws + off); off += (size_t)C_PAD * D_DIM * 2;  // 205.0 MB
    _Float16* memT = (_Float16*)(ws + off); off += (size_t)C_PAD * D_DIM * 2;  // 205.0 MB
    float* s_c     = (float*)(ws + off);    off += (size_t)C_PAD * 4;          // 0.4 MB
    _Float16* cuH  = (_Float16*)(ws + off); off += (size_t)B_ROWS * D_DIM * 2; // 0.5 MB
    _Float16* P    = (_Float16*)(ws + off); off += (size_t)B_ROWS * C_PAD * 2; // 51.2 MB
    float* den     = (float*)(ws + off);    off += 1024;
    float* num     = (float*)(ws + off);    off += (size_t)B_ROWS * D_DIM * 4; // 1 MB
    float* cur     = (float*)(ws + off);    off += (size_t)B_ROWS * D_DIM * 4; // 1 MB

    prep_mem_kernel<<<dim3(C_PAD), dim3(64), 0, stream>>>(mem, memH, s_c);
    transpose_kernel<<<dim3(C_PAD / 64, D_DIM / 64), dim3(256), 0, stream>>>(memH, memT);
    prep_cur_kernel<<<dim3(B_ROWS), dim3(64), 0, stream>>>(query, cuH, num, den);

    const float* cin = query;
    for (int st = 0; st < STEPS; ++st) {
        float* cout = (st == STEPS - 1) ? out : cur;
        gemm1_kernel<<<dim3(2, N_CTILES), dim3(256), 0, stream>>>(cuH, memH, s_c, P);
        gemm2_kernel<<<dim3(16, SPLITK), dim3(256), 0, stream>>>(P, memT, num, den);
        update_kernel<<<dim3(B_ROWS), dim3(256), 0, stream>>>(num, den, cin, cout, cuH);
        cin = cout;
    }
}